// Round 4
// baseline (732.572 us; speedup 1.0000x reference)
//
#include <hip/hip_runtime.h>
#include <hip/hip_bf16.h>

typedef unsigned int u32;
typedef unsigned short u16;

__device__ __forceinline__ u16 f2bf(float f){ u32 x; __builtin_memcpy(&x,&f,4); u32 r=(x+0x7fffu+((x>>16)&1u))>>16; return (u16)r; }
__device__ __forceinline__ float lo2f(u32 u){ u32 x=u<<16; float f; __builtin_memcpy(&f,&x,4); return f; }
__device__ __forceinline__ float hi2f(u32 u){ u32 x=u&0xffff0000u; float f; __builtin_memcpy(&f,&x,4); return f; }

// ---------------- K1/K3: split-K GEMM: (32 x K f32) @ (K x N f32) -> partials ----------------
// grid: (N/512, splits), block 256. Thread covers cols j, j+1.
__global__ __launch_bounds__(256) void gemm_splitk(
    const float* __restrict__ A, const float2* __restrict__ W2,
    float* __restrict__ P, int K, int N, int dps)
{
    const int t = threadIdx.x;
    const int j = blockIdx.x*512 + 2*t;
    const int s = blockIdx.y;
    float acc0[32], acc1[32];
    #pragma unroll
    for (int b=0;b<32;++b){ acc0[b]=0.f; acc1[b]=0.f; }
    const int d0 = s*dps, d1 = d0+dps;
    const int halfN = N>>1;
    #pragma unroll 2
    for (int d=d0; d<d1; ++d) {
        const float2 wp = W2[(size_t)d*halfN + (j>>1)];
        #pragma unroll
        for (int b=0;b<32;++b) {
            const float av = A[b*K + d];
            acc0[b] = fmaf(av, wp.x, acc0[b]);
            acc1[b] = fmaf(av, wp.y, acc1[b]);
        }
    }
    float* Pp = P + (size_t)(s*32)*N + j;
    #pragma unroll
    for (int b=0;b<32;++b) {
        *reinterpret_cast<float2*>(Pp + (size_t)b*N) = make_float2(acc0[b], acc1[b]);
    }
}

// ---------------- K2: reduce partials + RoPE + pack q/k/v ----------------
// grid: (6144/256, 32)
__global__ __launch_bounds__(256) void qkv_finish(
    const float* __restrict__ P, const float* __restrict__ cosc,
    const float* __restrict__ sinc, const int* __restrict__ spp,
    float* __restrict__ qws, float* __restrict__ kn, float* __restrict__ vn,
    int splits)
{
    const int col = blockIdx.x*256 + threadIdx.x;
    const int b = blockIdx.y;
    float v = 0.f;
    for (int s=0;s<splits;++s) v += P[(size_t)(s*32+b)*6144 + col];
    if (col < 5120) {
        const int d = col & 127;
        const int partner = (col & ~127) | ((d<64)? d+64 : d-64);
        float pv = 0.f;
        for (int s=0;s<splits;++s) pv += P[(size_t)(s*32+b)*6144 + partner];
        const int spos = *spp;
        const float c  = cosc[spos*128 + d];
        const float sn = sinc[spos*128 + d];
        const float rot = (d<64)? -pv : pv;
        const float val = fmaf(v, c, rot*sn);
        if (col < 4096) qws[(size_t)b*4096 + col] = val;
        else            kn[(size_t)b*1024 + (col-4096)] = val;
    } else {
        vn[(size_t)b*1024 + (col-5120)] = v;
    }
}

// ---------------- K4: fused attention over the KV cache ----------------
// grid: 256 blocks = (b, kv), block 256 = 4 waves.
__global__ __launch_bounds__(256) void attn_kernel(
    const float* __restrict__ qws, const float* __restrict__ Kc,
    const float* __restrict__ Vc, const float* __restrict__ kn,
    const float* __restrict__ vn, const float* __restrict__ mask,
    const int* __restrict__ curp, float* __restrict__ aout,
    const int PL, const int SW)
{
    __shared__ uint2 probsP[4096];        // 4 bf16 probs per position (h0..h3)
    __shared__ float obuf[4][4][128];     // [wave][head][d]
    __shared__ float redm[4][4];
    __shared__ float reds[4][4];

    const int t = threadIdx.x;
    const int lane = t & 63;
    const int w = t >> 6;
    const int b  = blockIdx.x >> 3;
    const int kv = blockIdx.x & 7;
    const int cur = *curp;

    const size_t mat = (size_t)(b*8+kv);
    const float* __restrict__ Kb  = Kc + mat*(size_t)SW*128;
    const float* __restrict__ knr = kn + mat*128;
    const float* __restrict__ qbase = qws + (size_t)(b*32 + kv*4)*128;

    // ---- Phase A: scores s[h][i] for positions p = i*256 + t ----
    float s[4][16];
    #pragma unroll
    for (int h=0;h<4;++h)
        #pragma unroll
        for (int i=0;i<16;++i) s[h][i]=0.f;

    for (int dc=0; dc<16; ++dc) {
        float qv[4][8];  // wave-uniform -> scalar loads
        #pragma unroll
        for (int h=0;h<4;++h)
            #pragma unroll
            for (int j=0;j<8;++j)
                qv[h][j] = qbase[h*128 + dc*8 + j];
        #pragma unroll
        for (int i=0;i<16;++i) {
            const int p = i*256 + t;
            const int pc = (p < SW) ? p : 0;
            const float* row = (p==cur) ? knr : (Kb + (size_t)pc*128);
            const float4 ka = *reinterpret_cast<const float4*>(row + dc*8);
            const float4 kb = *reinterpret_cast<const float4*>(row + dc*8 + 4);
            float kf[8];
            kf[0]=ka.x; kf[1]=ka.y; kf[2]=ka.z; kf[3]=ka.w;
            kf[4]=kb.x; kf[5]=kb.y; kf[6]=kb.z; kf[7]=kb.w;
            #pragma unroll
            for (int h=0;h<4;++h)
                #pragma unroll
                for (int j=0;j<8;++j)
                    s[h][i] = fmaf(qv[h][j], kf[j], s[h][i]);
        }
    }

    // ---- scale + mask (+ invalidate tail) ----
    const float scale = 0.08838834764831845f; // 1/sqrt(128)
    const size_t mbase = ((size_t)b*32 + (size_t)kv*4)*(size_t)PL;
    #pragma unroll
    for (int i=0;i<16;++i) {
        const int p = i*256 + t;
        if (p < PL) {
            #pragma unroll
            for (int h=0;h<4;++h) {
                const float mv = mask[mbase + (size_t)h*PL + p];
                s[h][i] = fmaf(s[h][i], scale, mv);
            }
        } else {
            #pragma unroll
            for (int h=0;h<4;++h) s[h][i] = -3.0e38f;
        }
    }

    // ---- softmax: block max ----
    float lm[4];
    #pragma unroll
    for (int h=0;h<4;++h) {
        lm[h] = s[h][0];
        #pragma unroll
        for (int i=1;i<16;++i) lm[h] = fmaxf(lm[h], s[h][i]);
    }
    #pragma unroll
    for (int off=1; off<64; off<<=1) {
        #pragma unroll
        for (int h=0;h<4;++h) lm[h] = fmaxf(lm[h], __shfl_xor(lm[h], off, 64));
    }
    if (lane==0) {
        #pragma unroll
        for (int h=0;h<4;++h) redm[w][h] = lm[h];
    }
    __syncthreads();
    float M[4];
    #pragma unroll
    for (int h=0;h<4;++h)
        M[h] = fmaxf(fmaxf(redm[0][h],redm[1][h]), fmaxf(redm[2][h],redm[3][h]));

    // ---- exp + block sum ----
    float ls[4] = {0.f,0.f,0.f,0.f};
    #pragma unroll
    for (int i=0;i<16;++i) {
        #pragma unroll
        for (int h=0;h<4;++h) {
            const float e = __expf(s[h][i] - M[h]);
            s[h][i] = e;
            ls[h] += e;
        }
    }
    #pragma unroll
    for (int off=1; off<64; off<<=1) {
        #pragma unroll
        for (int h=0;h<4;++h) ls[h] += __shfl_xor(ls[h], off, 64);
    }
    if (lane==0) {
        #pragma unroll
        for (int h=0;h<4;++h) reds[w][h] = ls[h];
    }
    __syncthreads();
    float inv[4];
    #pragma unroll
    for (int h=0;h<4;++h)
        inv[h] = 1.f / (reds[0][h]+reds[1][h]+reds[2][h]+reds[3][h]);

    // ---- write normalized probs (bf16 packed) ----
    #pragma unroll
    for (int i=0;i<16;++i) {
        const int p = i*256 + t;
        if (p < PL) {
            const u32 plo = (u32)f2bf(s[0][i]*inv[0]) | ((u32)f2bf(s[1][i]*inv[1]) << 16);
            const u32 phi = (u32)f2bf(s[2][i]*inv[2]) | ((u32)f2bf(s[3][i]*inv[3]) << 16);
            probsP[p] = make_uint2(plo, phi);
        }
    }
    __syncthreads();

    // ---- Phase PV: wave w covers positions [w*PL/4, (w+1)*PL/4), lane covers d=2*lane,2*lane+1 ----
    const float* __restrict__ Vb  = Vc + mat*(size_t)SW*128;
    const float* __restrict__ vnr = vn + mat*128;
    const int chunk = PL >> 2;
    const int p0 = w*chunk, p1 = p0 + chunk;
    float a0[4] = {0.f,0.f,0.f,0.f}, a1[4] = {0.f,0.f,0.f,0.f};
    #pragma unroll 4
    for (int p=p0; p<p1; ++p) {
        const float* row = (p==cur) ? vnr : (Vb + (size_t)p*128);
        const float2 vv = *reinterpret_cast<const float2*>(row + 2*lane);
        const uint2 pp = probsP[p];
        const float pr0 = lo2f(pp.x), pr1 = hi2f(pp.x);
        const float pr2 = lo2f(pp.y), pr3 = hi2f(pp.y);
        a0[0]=fmaf(pr0,vv.x,a0[0]); a1[0]=fmaf(pr0,vv.y,a1[0]);
        a0[1]=fmaf(pr1,vv.x,a0[1]); a1[1]=fmaf(pr1,vv.y,a1[1]);
        a0[2]=fmaf(pr2,vv.x,a0[2]); a1[2]=fmaf(pr2,vv.y,a1[2]);
        a0[3]=fmaf(pr3,vv.x,a0[3]); a1[3]=fmaf(pr3,vv.y,a1[3]);
    }
    #pragma unroll
    for (int h=0;h<4;++h)
        *reinterpret_cast<float2*>(&obuf[w][h][2*lane]) = make_float2(a0[h], a1[h]);
    __syncthreads();

    // ---- cross-wave reduce + writeout ----
    #pragma unroll
    for (int r=0;r<2;++r) {
        const int idx = r*256 + t;
        const int h = idx >> 7;
        const int d = idx & 127;
        const float sum = obuf[0][h][d]+obuf[1][h][d]+obuf[2][h][d]+obuf[3][h][d];
        aout[(size_t)(b*32 + kv*4 + h)*128 + d] = sum;
    }
}

// ---------------- K5: reduce wo partials -> f32 output ----------------
// grid: (4096/256, 32)
__global__ __launch_bounds__(256) void wo_finish(
    const float* __restrict__ P, float* __restrict__ out, int splits)
{
    const int col = blockIdx.x*256 + threadIdx.x;
    const int b = blockIdx.y;
    float v = 0.f;
    for (int s=0;s<splits;++s) v += P[(size_t)(s*32+b)*4096 + col];
    out[(size_t)b*4096 + col] = v;
}

extern "C" void kernel_launch(void* const* d_in, const int* in_sizes, int n_in,
                              void* d_out, int out_size, void* d_ws, size_t ws_size,
                              hipStream_t stream)
{
    const float* x    = (const float*)d_in[0];
    const float* wqkv = (const float*)d_in[1];
    const float* wo   = (const float*)d_in[2];
    const float* cK   = (const float*)d_in[3];
    const float* cV   = (const float*)d_in[4];
    const float* cosc = (const float*)d_in[5];
    const float* sinc = (const float*)d_in[6];
    const float* mask = (const float*)d_in[7];
    const int* sp   = (const int*)d_in[8];
    const int* cp   = (const int*)d_in[9];

    const int PL = in_sizes[7] / (32*32);          // padded_len (4032)
    const int SW = in_sizes[3] / (32*8*128);       // cache rows (4096)

    char* ws = (char*)d_ws;
    float* qws  = (float*)(ws);                          // 512 KB
    float* aout = (float*)(ws + 524288);                 // 512 KB
    float* kn   = (float*)(ws + 2*524288);               // 128 KB
    float* vn   = (float*)(ws + 2*524288 + 131072);      // 128 KB
    float* Pbuf = (float*)(ws + 2*524288 + 2*131072);    // split-K partials

    // pick split count that fits the workspace (4096 % splits == 0)
    int splits = 32;
    {
        const size_t fixed = 2ull*524288 + 2ull*131072;
        while (splits > 4 && fixed + (size_t)splits*32*6144*4 > ws_size) splits >>= 1;
    }
    const int dps = 4096 / splits;

    gemm_splitk<<<dim3(12, splits), 256, 0, stream>>>(x, (const float2*)wqkv, Pbuf, 4096, 6144, dps);
    qkv_finish<<<dim3(24, 32), 256, 0, stream>>>(Pbuf, cosc, sinc, sp, qws, kn, vn, splits);

    attn_kernel<<<256, 256, 0, stream>>>(qws, cK, cV, kn, vn, mask, cp, aout, PL, SW);

    gemm_splitk<<<dim3(8, splits), 256, 0, stream>>>(aout, (const float2*)wo, Pbuf, 4096, 4096, dps);
    wo_finish<<<dim3(16, 32), 256, 0, stream>>>(Pbuf, (float*)d_out, splits);
}

// Round 5
// 453.306 us; speedup vs baseline: 1.6161x; 1.6161x over previous
//
#include <hip/hip_runtime.h>
#include <hip/hip_bf16.h>

typedef unsigned int u32;
typedef unsigned short u16;

__device__ __forceinline__ u16 f2bf(float f){ u32 x; __builtin_memcpy(&x,&f,4); u32 r=(x+0x7fffu+((x>>16)&1u))>>16; return (u16)r; }
__device__ __forceinline__ float lo2f(u32 u){ u32 x=u<<16; float f; __builtin_memcpy(&f,&x,4); return f; }
__device__ __forceinline__ float hi2f(u32 u){ u32 x=u&0xffff0000u; float f; __builtin_memcpy(&f,&x,4); return f; }

// ---------------- K1/K3: split-K GEMM: (32 x K f32) @ (K x N f32) -> partials ----------------
__global__ __launch_bounds__(256) void gemm_splitk(
    const float* __restrict__ A, const float2* __restrict__ W2,
    float* __restrict__ P, int K, int N, int dps)
{
    const int t = threadIdx.x;
    const int j = blockIdx.x*512 + 2*t;
    const int s = blockIdx.y;
    float acc0[32], acc1[32];
    #pragma unroll
    for (int b=0;b<32;++b){ acc0[b]=0.f; acc1[b]=0.f; }
    const int d0 = s*dps, d1 = d0+dps;
    const int halfN = N>>1;
    #pragma unroll 2
    for (int d=d0; d<d1; ++d) {
        const float2 wp = W2[(size_t)d*halfN + (j>>1)];
        #pragma unroll
        for (int b=0;b<32;++b) {
            const float av = A[b*K + d];
            acc0[b] = fmaf(av, wp.x, acc0[b]);
            acc1[b] = fmaf(av, wp.y, acc1[b]);
        }
    }
    float* Pp = P + (size_t)(s*32)*N + j;
    #pragma unroll
    for (int b=0;b<32;++b) {
        *reinterpret_cast<float2*>(Pp + (size_t)b*N) = make_float2(acc0[b], acc1[b]);
    }
}

// ---------------- K2: reduce partials + RoPE + pack q/k/v ----------------
__global__ __launch_bounds__(256) void qkv_finish(
    const float* __restrict__ P, const float* __restrict__ cosc,
    const float* __restrict__ sinc, const int* __restrict__ spp,
    float* __restrict__ qws, float* __restrict__ kn, float* __restrict__ vn,
    int splits)
{
    const int col = blockIdx.x*256 + threadIdx.x;
    const int b = blockIdx.y;
    float v = 0.f;
    for (int s=0;s<splits;++s) v += P[(size_t)(s*32+b)*6144 + col];
    if (col < 5120) {
        const int d = col & 127;
        const int partner = (col & ~127) | ((d<64)? d+64 : d-64);
        float pv = 0.f;
        for (int s=0;s<splits;++s) pv += P[(size_t)(s*32+b)*6144 + partner];
        const int spos = *spp;
        const float c  = cosc[spos*128 + d];
        const float sn = sinc[spos*128 + d];
        const float rot = (d<64)? -pv : pv;
        const float val = fmaf(v, c, rot*sn);
        if (col < 4096) qws[(size_t)b*4096 + col] = val;
        else            kn[(size_t)b*1024 + (col-4096)] = val;
    } else {
        vn[(size_t)b*1024 + (col-5120)] = v;
    }
}

// ---------------- K4: fused attention, 1024 threads = 16 waves per (b,kv) block ----------------
__global__ __launch_bounds__(1024, 4) void attn_kernel(
    const float* __restrict__ qws, const float* __restrict__ Kc,
    const float* __restrict__ Vc, const float* __restrict__ kn,
    const float* __restrict__ vn, const float* __restrict__ mask,
    const int* __restrict__ curp, float* __restrict__ aout,
    const int PL, const int SW)
{
    __shared__ uint2 probsP[4096];        // 32 KB: 4 bf16 probs per position
    __shared__ float obuf[16][4][128];    // 32 KB: [wave][head][d]
    __shared__ float redm[16][4];
    __shared__ float reds[16][4];

    const int t = threadIdx.x;
    const int lane = t & 63;
    const int w = t >> 6;
    const int b  = blockIdx.x >> 3;
    const int kv = blockIdx.x & 7;
    const int cur = *curp;

    const size_t mat = (size_t)(b*8+kv);
    const float* __restrict__ Kb  = Kc + mat*(size_t)SW*128;
    const float* __restrict__ knr = kn + mat*128;
    const float* __restrict__ qbase = qws + (size_t)(b*32 + kv*4)*128;

    // ---- Phase A: scores. Thread covers p = i*1024 + t, i=0..3; row streamed dc-inner. ----
    float s[4][4];   // [head][i]
    #pragma unroll
    for (int i=0;i<4;++i) {
        const int p = i*1024 + t;
        float acc0=0.f, acc1=0.f, acc2=0.f, acc3=0.f;
        if (p < PL) {
            const float* __restrict__ row = (p==cur) ? knr : (Kb + (size_t)p*128);
            #pragma unroll
            for (int dc=0; dc<16; ++dc) {
                const float4 ka = *reinterpret_cast<const float4*>(row + dc*8);
                const float4 kb = *reinterpret_cast<const float4*>(row + dc*8 + 4);
                const float* __restrict__ q0 = qbase + dc*8;
                #pragma unroll
                for (int j=0;j<4;++j) {
                    const float kj = (j==0)?ka.x:(j==1)?ka.y:(j==2)?ka.z:ka.w;
                    acc0 = fmaf(q0[j      ], kj, acc0);
                    acc1 = fmaf(q0[j+128  ], kj, acc1);
                    acc2 = fmaf(q0[j+256  ], kj, acc2);
                    acc3 = fmaf(q0[j+384  ], kj, acc3);
                }
                #pragma unroll
                for (int j=0;j<4;++j) {
                    const float kj = (j==0)?kb.x:(j==1)?kb.y:(j==2)?kb.z:kb.w;
                    acc0 = fmaf(q0[j+4    ], kj, acc0);
                    acc1 = fmaf(q0[j+132  ], kj, acc1);
                    acc2 = fmaf(q0[j+260  ], kj, acc2);
                    acc3 = fmaf(q0[j+388  ], kj, acc3);
                }
            }
        }
        s[0][i]=acc0; s[1][i]=acc1; s[2][i]=acc2; s[3][i]=acc3;
    }

    // ---- scale + mask (+ invalidate tail) ----
    const float scale = 0.08838834764831845f; // 1/sqrt(128)
    const size_t mbase = ((size_t)b*32 + (size_t)kv*4)*(size_t)PL;
    #pragma unroll
    for (int i=0;i<4;++i) {
        const int p = i*1024 + t;
        if (p < PL) {
            #pragma unroll
            for (int h=0;h<4;++h) {
                const float mv = mask[mbase + (size_t)h*PL + p];
                s[h][i] = fmaf(s[h][i], scale, mv);
            }
        } else {
            #pragma unroll
            for (int h=0;h<4;++h) s[h][i] = -3.0e38f;
        }
    }

    // ---- softmax: block max over 16 waves ----
    float lm[4];
    #pragma unroll
    for (int h=0;h<4;++h) {
        lm[h] = fmaxf(fmaxf(s[h][0],s[h][1]), fmaxf(s[h][2],s[h][3]));
    }
    #pragma unroll
    for (int off=1; off<64; off<<=1) {
        #pragma unroll
        for (int h=0;h<4;++h) lm[h] = fmaxf(lm[h], __shfl_xor(lm[h], off, 64));
    }
    if (lane==0) {
        #pragma unroll
        for (int h=0;h<4;++h) redm[w][h] = lm[h];
    }
    __syncthreads();
    float M[4];
    #pragma unroll
    for (int h=0;h<4;++h) {
        float m = redm[0][h];
        #pragma unroll
        for (int ww=1;ww<16;++ww) m = fmaxf(m, redm[ww][h]);
        M[h] = m;
    }

    // ---- exp + block sum ----
    float ls[4] = {0.f,0.f,0.f,0.f};
    #pragma unroll
    for (int i=0;i<4;++i) {
        #pragma unroll
        for (int h=0;h<4;++h) {
            const float e = __expf(s[h][i] - M[h]);
            s[h][i] = e;
            ls[h] += e;
        }
    }
    #pragma unroll
    for (int off=1; off<64; off<<=1) {
        #pragma unroll
        for (int h=0;h<4;++h) ls[h] += __shfl_xor(ls[h], off, 64);
    }
    if (lane==0) {
        #pragma unroll
        for (int h=0;h<4;++h) reds[w][h] = ls[h];
    }
    __syncthreads();
    float inv[4];
    #pragma unroll
    for (int h=0;h<4;++h) {
        float sm = reds[0][h];
        #pragma unroll
        for (int ww=1;ww<16;++ww) sm += reds[ww][h];
        inv[h] = 1.f / sm;
    }

    // ---- write normalized probs (bf16 packed) ----
    #pragma unroll
    for (int i=0;i<4;++i) {
        const int p = i*1024 + t;
        if (p < PL) {
            const u32 plo = (u32)f2bf(s[0][i]*inv[0]) | ((u32)f2bf(s[1][i]*inv[1]) << 16);
            const u32 phi = (u32)f2bf(s[2][i]*inv[2]) | ((u32)f2bf(s[3][i]*inv[3]) << 16);
            probsP[p] = make_uint2(plo, phi);
        }
    }
    __syncthreads();

    // ---- Phase PV: wave w covers positions [w*PL/16, (w+1)*PL/16), lane covers d=2*lane,2*lane+1 ----
    const float* __restrict__ Vb  = Vc + mat*(size_t)SW*128;
    const float* __restrict__ vnr = vn + mat*128;
    const int chunk = PL >> 4;
    const int p0 = w*chunk, p1 = p0 + chunk;
    float a0[4] = {0.f,0.f,0.f,0.f}, a1[4] = {0.f,0.f,0.f,0.f};
    #pragma unroll 4
    for (int p=p0; p<p1; ++p) {
        const float* row = (p==cur) ? vnr : (Vb + (size_t)p*128);
        const float2 vv = *reinterpret_cast<const float2*>(row + 2*lane);
        const uint2 pp = probsP[p];
        const float pr0 = lo2f(pp.x), pr1 = hi2f(pp.x);
        const float pr2 = lo2f(pp.y), pr3 = hi2f(pp.y);
        a0[0]=fmaf(pr0,vv.x,a0[0]); a1[0]=fmaf(pr0,vv.y,a1[0]);
        a0[1]=fmaf(pr1,vv.x,a0[1]); a1[1]=fmaf(pr1,vv.y,a1[1]);
        a0[2]=fmaf(pr2,vv.x,a0[2]); a1[2]=fmaf(pr2,vv.y,a1[2]);
        a0[3]=fmaf(pr3,vv.x,a0[3]); a1[3]=fmaf(pr3,vv.y,a1[3]);
    }
    #pragma unroll
    for (int h=0;h<4;++h)
        *reinterpret_cast<float2*>(&obuf[w][h][2*lane]) = make_float2(a0[h], a1[h]);
    __syncthreads();

    // ---- cross-wave reduce + writeout ----
    if (t < 512) {
        const int h = t >> 7;
        const int d = t & 127;
        float sum = obuf[0][h][d];
        #pragma unroll
        for (int ww=1;ww<16;++ww) sum += obuf[ww][h][d];
        aout[(size_t)(b*32 + kv*4 + h)*128 + d] = sum;
    }
}

// ---------------- K5: reduce wo partials -> f32 output ----------------
__global__ __launch_bounds__(256) void wo_finish(
    const float* __restrict__ P, float* __restrict__ out, int splits)
{
    const int col = blockIdx.x*256 + threadIdx.x;
    const int b = blockIdx.y;
    float v = 0.f;
    for (int s=0;s<splits;++s) v += P[(size_t)(s*32+b)*4096 + col];
    out[(size_t)b*4096 + col] = v;
}

extern "C" void kernel_launch(void* const* d_in, const int* in_sizes, int n_in,
                              void* d_out, int out_size, void* d_ws, size_t ws_size,
                              hipStream_t stream)
{
    const float* x    = (const float*)d_in[0];
    const float* wqkv = (const float*)d_in[1];
    const float* wo   = (const float*)d_in[2];
    const float* cK   = (const float*)d_in[3];
    const float* cV   = (const float*)d_in[4];
    const float* cosc = (const float*)d_in[5];
    const float* sinc = (const float*)d_in[6];
    const float* mask = (const float*)d_in[7];
    const int* sp   = (const int*)d_in[8];
    const int* cp   = (const int*)d_in[9];

    const int PL = in_sizes[7] / (32*32);          // padded_len (4032)
    const int SW = in_sizes[3] / (32*8*128);       // cache rows (4096)

    char* ws = (char*)d_ws;
    float* qws  = (float*)(ws);                          // 512 KB
    float* aout = (float*)(ws + 524288);                 // 512 KB
    float* kn   = (float*)(ws + 2*524288);               // 128 KB
    float* vn   = (float*)(ws + 2*524288 + 131072);      // 128 KB
    float* Pbuf = (float*)(ws + 2*524288 + 2*131072);    // split-K partials

    int splits = 32;
    {
        const size_t fixed = 2ull*524288 + 2ull*131072;
        while (splits > 4 && fixed + (size_t)splits*32*6144*4 > ws_size) splits >>= 1;
    }
    const int dps = 4096 / splits;

    gemm_splitk<<<dim3(12, splits), 256, 0, stream>>>(x, (const float2*)wqkv, Pbuf, 4096, 6144, dps);
    qkv_finish<<<dim3(24, 32), 256, 0, stream>>>(Pbuf, cosc, sinc, sp, qws, kn, vn, splits);

    attn_kernel<<<256, 1024, 0, stream>>>(qws, cK, cV, kn, vn, mask, cp, aout, PL, SW);

    gemm_splitk<<<dim3(8, splits), 256, 0, stream>>>(aout, (const float2*)wo, Pbuf, 4096, 4096, dps);
    wo_finish<<<dim3(16, 32), 256, 0, stream>>>(Pbuf, (float*)d_out, splits);
}